// Round 8
// baseline (479.119 us; speedup 1.0000x reference)
//
#include <hip/hip_runtime.h>
#include <hip/hip_fp16.h>

#define DIM 256
#define MARGIN 2.25e-4f
#define WLCAP 262144

typedef __bf16 bf8v __attribute__((ext_vector_type(8)));
typedef float f4v __attribute__((ext_vector_type(4)));

__device__ inline unsigned short f2bf(float x) {
    unsigned u = __float_as_uint(x);
    u += 0x7fffu + ((u >> 16) & 1u);   // RNE
    return (unsigned short)(u >> 16);
}

// ---------------- transpose z [8,256,32,32] -> zf [8192,256] fp32 + zb bf16 ----------------
__global__ __launch_bounds__(256) void k_zprep(const float* __restrict__ z,
                                               float* __restrict__ zf,
                                               unsigned short* __restrict__ zb) {
    __shared__ float t[32][33];
    const int hw0 = blockIdx.x * 32;
    const int d0  = blockIdx.y * 32;
    const int b   = blockIdx.z;
    const int tx = threadIdx.x & 31, ty = threadIdx.x >> 5;
#pragma unroll
    for (int i = 0; i < 4; i++) {
        const int d = d0 + ty + 8 * i;
        t[ty + 8 * i][tx] = z[(b * 256 + d) * 1024 + hw0 + tx];
    }
    __syncthreads();
#pragma unroll
    for (int i = 0; i < 4; i++) {
        const int hw = hw0 + ty + 8 * i;
        const float v = t[tx][ty + 8 * i];
        const size_t o = (size_t)(b * 1024 + hw) * DIM + d0 + tx;
        zf[o] = v;
        zb[o] = f2bf(v);
    }
}

// ---------------- emb -> eb bf16 + enorm; also zero worklist counter ----------------
__global__ __launch_bounds__(256) void k_eprep(const float* __restrict__ emb,
                                               unsigned short* __restrict__ eb,
                                               float* __restrict__ enorm,
                                               int* __restrict__ gcnt) {
    if (blockIdx.x == 0 && threadIdx.x == 0) gcnt[0] = 0;
    const int wave = threadIdx.x >> 6, lane = threadIdx.x & 63;
    const int row = blockIdx.x * 4 + wave;
    const float4 v = *(const float4*)(emb + (size_t)row * DIM + lane * 4);
    ushort4 o;
    o.x = f2bf(v.x); o.y = f2bf(v.y); o.z = f2bf(v.z); o.w = f2bf(v.w);
    *(ushort4*)(eb + (size_t)row * DIM + lane * 4) = o;
    float s = v.x * v.x + v.y * v.y + v.z * v.z + v.w * v.w;
#pragma unroll
    for (int m = 1; m < 64; m <<= 1) s += __shfl_xor(s, m, 64);
    if (lane == 0) enorm[row] = s;
}

// ---------------- rownorm over zf ----------------
__global__ __launch_bounds__(256) void k_rownorm(const float* __restrict__ src,
                                                 float* __restrict__ dst) {
    const int wave = threadIdx.x >> 6, lane = threadIdx.x & 63;
    const int row = blockIdx.x * 4 + wave;
    const float4 v = *(const float4*)(src + (size_t)row * DIM + lane * 4);
    float s = v.x * v.x + v.y * v.y + v.z * v.z + v.w * v.w;
#pragma unroll
    for (int m = 1; m < 64; m <<= 1) s += __shfl_xor(s, m, 64);
    if (lane == 0) dst[row] = s;
}

// ---------------- panel-persistent bf16 MFMA scoring ----------------
// Block owns a 64-code panel p = blockIdx.x & 255 (staged once in LDS, swizzled),
// and streams rows [qtr*2048, +2048) of zb against it. No barrier in the K-loop.
// Group g = p*4 + (m15>>2): codes p*64 + ct*16 + (m15>>2)*4 + l  (l = m15&3)
// pvalh[row][g] = fp16( min over the group's 16 codes of (en - 2*dot_bf16) )
__global__ __launch_bounds__(256, 4) void k_score(
        const unsigned short* __restrict__ zb, const unsigned short* __restrict__ eb,
        const float* __restrict__ enorm, unsigned short* __restrict__ pvalh) {
    __shared__ unsigned short Bs[64 * 256];   // 32 KB, chunk-swizzled
    const int p   = blockIdx.x & 255;
    const int qtr = blockIdx.x >> 8;
    const int t = threadIdx.x;
    const int wave = t >> 6, lane = t & 63;
    const int q = lane >> 4, m15 = lane & 15;

    // stage the 64x256 bf16 panel: 2048 16B-chunks, swizzle chunk c -> c ^ (r&7)
#pragma unroll
    for (int i = 0; i < 8; i++) {
        const int id = t + i * 256;
        const int r = id >> 5, c = id & 31;
        const uint4 v = *(const uint4*)(eb + (size_t)(p * 64 + r) * DIM + c * 8);
        *(uint4*)&Bs[r * 256 + ((c ^ (r & 7)) * 8)] = v;
    }
    __syncthreads();

    float en_l[4];
#pragma unroll
    for (int ct = 0; ct < 4; ct++) en_l[ct] = enorm[p * 64 + ct * 16 + m15];

    const int g = p * 4 + (m15 >> 2);

    for (int slab = 0; slab < 8; slab++) {
        const int row0 = qtr * 2048 + slab * 256 + wave * 64;
        const unsigned short* a0 = zb + (size_t)(row0 + m15) * DIM + q * 8;

        f4v acc[4][4];
#pragma unroll
        for (int rt = 0; rt < 4; rt++)
#pragma unroll
            for (int ct = 0; ct < 4; ct++) acc[rt][ct] = (f4v){0.f, 0.f, 0.f, 0.f};

#pragma unroll
        for (int ks = 0; ks < 8; ks++) {
            bf8v af[4], bfv[4];
#pragma unroll
            for (int rt = 0; rt < 4; rt++)
                af[rt] = *(const bf8v*)(a0 + rt * 16 * DIM + ks * 32);
#pragma unroll
            for (int ct = 0; ct < 4; ct++)
                bfv[ct] = *(const bf8v*)&Bs[(ct * 16 + m15) * 256 + (((ks * 4 + q) ^ (m15 & 7)) * 8)];
#pragma unroll
            for (int rt = 0; rt < 4; rt++)
#pragma unroll
                for (int ct = 0; ct < 4; ct++)
                    acc[rt][ct] = __builtin_amdgcn_mfma_f32_16x16x32_bf16(af[rt], bfv[ct], acc[rt][ct], 0, 0, 0);
        }

        // epilogue: s = en - 2*dot (filter-only); min over ct, then l = m15&3
#pragma unroll
        for (int rt = 0; rt < 4; rt++) {
            float sv[4];
#pragma unroll
            for (int j = 0; j < 4; j++) {
                float s = fmaf(-2.f, acc[rt][0][j], en_l[0]);
#pragma unroll
                for (int ct = 1; ct < 4; ct++)
                    s = fminf(s, fmaf(-2.f, acc[rt][ct][j], en_l[ct]));
                sv[j] = s;
            }
#pragma unroll
            for (int m = 1; m <= 2; m <<= 1)
#pragma unroll
                for (int j = 0; j < 4; j++)
                    sv[j] = fminf(sv[j], __shfl_xor(sv[j], m, 64));
            if ((m15 & 3) == 0) {
                const int row = row0 + rt * 16 + q * 4;
#pragma unroll
                for (int j = 0; j < 4; j++)
                    pvalh[(size_t)(row + j) * 1024 + g] = __half_as_ushort(__float2half_rn(sv[j]));
            }
        }
    }
}

// ---------------- flag: per row, min over 1024 group-mins; append flagged to worklist ------------
__global__ __launch_bounds__(256) void k_flag(const unsigned short* __restrict__ pvalh,
                                              unsigned long long* __restrict__ best64,
                                              int* __restrict__ wl, int* __restrict__ gcnt) {
    const int row = blockIdx.x;
    const int t = threadIdx.x;
    const int lane = t & 63, w = t >> 6;
    __shared__ float wmin[4];
    __shared__ int lcnt, lbase;
    __shared__ int llist[1024];
    if (t == 0) { lcnt = 0; best64[row] = 0xFFFFFFFFFFFFFFFFULL; }
    const __half* p = (const __half*)(pvalh + (size_t)row * 1024 + t * 4);
    float v[4];
#pragma unroll
    for (int k = 0; k < 4; k++) v[k] = __half2float(p[k]);
    float mn = fminf(fminf(v[0], v[1]), fminf(v[2], v[3]));
#pragma unroll
    for (int m = 1; m < 64; m <<= 1) mn = fminf(mn, __shfl_xor(mn, m, 64));
    if (lane == 0) wmin[w] = mn;
    __syncthreads();
    const float g = fminf(fminf(wmin[0], wmin[1]), fminf(wmin[2], wmin[3])) + MARGIN;
#pragma unroll
    for (int k = 0; k < 4; k++) {
        if (v[k] <= g) {
            const int pos = atomicAdd(&lcnt, 1);
            llist[pos] = (row << 10) | (t * 4 + k);
        }
    }
    __syncthreads();
    if (t == 0) lbase = atomicAdd(gcnt, lcnt);
    __syncthreads();
    for (int i = t; i < lcnt; i += 256) {
        const int d = lbase + i;
        if (d < WLCAP) wl[d] = llist[i];
    }
}

// ---------------- rescore: exact fp32 re-score of flagged 16-code (strided) groups --------------
__global__ __launch_bounds__(256) void k_rescore(
        const float* __restrict__ zf, const float* __restrict__ emb,
        const float* __restrict__ znorm, const float* __restrict__ enorm,
        const int* __restrict__ wl, const int* __restrict__ gcnt,
        unsigned long long* __restrict__ best64) {
    const int count = min(gcnt[0], WLCAP);
    const int t = threadIdx.x;
    const int lane16 = t & 15, codei = t >> 4;
    for (int item = blockIdx.x; item < count; item += gridDim.x) {
        const int e = wl[item];
        const int row = e >> 10, g = e & 1023;
        // group membership: code = (g>>2)*64 + ct*16 + (g&3)*4 + l
        const int cbase = ((g >> 2) << 6) + ((g & 3) << 2);
        const int code = cbase + ((codei >> 2) << 4) + (codei & 3);
        const float* zp = zf + (size_t)row * DIM + lane16 * 16;
        const float* ep = emb + (size_t)code * DIM + lane16 * 16;
        float d = 0.f;
#pragma unroll
        for (int k = 0; k < 16; k += 4) {
            const float4 ev = *(const float4*)(ep + k);
            const float4 zv = *(const float4*)(zp + k);
            d = fmaf(zv.x, ev.x, d);
            d = fmaf(zv.y, ev.y, d);
            d = fmaf(zv.z, ev.z, d);
            d = fmaf(zv.w, ev.w, d);
        }
#pragma unroll
        for (int m = 1; m <= 8; m <<= 1) d += __shfl_xor(d, m, 64);
        if (lane16 == 0) {
            const float tt = znorm[row] + enorm[code];
            const float s = tt - 2.0f * d;   // exact fp32 semantics
            const unsigned long long key =
                ((unsigned long long)__float_as_uint(s) << 32) | (unsigned)code;
            atomicMin(&best64[row], key);
        }
    }
}

// ---------------- out_idx from best64 ----------------
__global__ __launch_bounds__(256) void k_finalidx(const unsigned long long* __restrict__ best64,
                                                  float* __restrict__ out_idx) {
    const int i = blockIdx.x * 256 + threadIdx.x;
    out_idx[i] = (float)(unsigned)(best64[i] & 0xFFFFFFFFULL);
}

// ---------------- gather z_q (NCHW) + loss partials ----------------
__global__ __launch_bounds__(256) void k_gather(const float* __restrict__ emb,
                                                const float* __restrict__ zf,
                                                const unsigned long long* __restrict__ best64,
                                                float* __restrict__ zq,
                                                float* __restrict__ loss_part) {
    __shared__ float t[32][33];
    const int hw0 = blockIdx.x * 32;
    const int c0  = blockIdx.y * 32;
    const int b   = blockIdx.z;
    const int tx = threadIdx.x & 31, ty = threadIdx.x >> 5;
    float lsum = 0.f;
#pragma unroll
    for (int i = 0; i < 4; i++) {
        const int hh = ty + 8 * i;
        const int n = b * 1024 + hw0 + hh;
        const int id = (int)(best64[n] & 0xFFFFFFFFULL);
        const float q = emb[(size_t)id * DIM + c0 + tx];
        const float zv = zf[(size_t)n * DIM + c0 + tx];
        const float d = q - zv;
        lsum += d * d;
        t[hh][tx] = q;
    }
    __syncthreads();
#pragma unroll
    for (int i = 0; i < 4; i++) {
        const int c = c0 + ty + 8 * i;
        zq[(size_t)(b * 256 + c) * 1024 + hw0 + tx] = t[tx][ty + 8 * i];
    }
#pragma unroll
    for (int m = 1; m < 64; m <<= 1) lsum += __shfl_xor(lsum, m, 64);
    __shared__ float wsum[4];
    const int lane = threadIdx.x & 63, w = threadIdx.x >> 6;
    if (lane == 0) wsum[w] = lsum;
    __syncthreads();
    if (threadIdx.x == 0) {
        const int bid = (blockIdx.z * gridDim.y + blockIdx.y) * gridDim.x + blockIdx.x;
        loss_part[bid] = wsum[0] + wsum[1] + wsum[2] + wsum[3];
    }
}

// ---------------- finalize loss ----------------
__global__ __launch_bounds__(256) void k_final(const float* __restrict__ loss_part,
                                               float* __restrict__ out_loss) {
    float s = 0.f;
    for (int i = threadIdx.x; i < 2048; i += 256) s += loss_part[i];
#pragma unroll
    for (int m = 1; m < 64; m <<= 1) s += __shfl_xor(s, m, 64);
    __shared__ float wsum[4];
    const int lane = threadIdx.x & 63, w = threadIdx.x >> 6;
    if (lane == 0) wsum[w] = s;
    __syncthreads();
    if (threadIdx.x == 0) {
        out_loss[0] = 1.25f * (wsum[0] + wsum[1] + wsum[2] + wsum[3]) / 2097152.0f;
    }
}

extern "C" void kernel_launch(void* const* d_in, const int* in_sizes, int n_in,
                              void* d_out, int out_size, void* d_ws, size_t ws_size,
                              hipStream_t stream) {
    const float* z   = (const float*)d_in[0];   // [8,256,32,32]
    const float* emb = (const float*)d_in[1];   // [16384,256]
    float* out = (float*)d_out;
    float* ws  = (float*)d_ws;

    // ws layout (float-slot offsets):
    float*              zf    = ws;                                   // 2,097,152  (8 MB)
    unsigned short*     pvalh = (unsigned short*)(ws + 2097152);      // 8M halves  (16 MB)
    unsigned short*     zb    = (unsigned short*)(ws + 6291456);      // 2M halves  (4 MB)
    unsigned short*     eb    = (unsigned short*)(ws + 7340032);      // 4M halves  (8 MB)
    float*              enorm = ws + 9437184;                         // 16,384
    float*              znorm = ws + 9453568;                         // 8,192
    unsigned long long* best64= (unsigned long long*)(ws + 9461760);  // 8192 × 8 B
    int*                wl    = (int*)(ws + 9478144);                 // 262,144
    int*                gcnt  = (int*)(ws + 9740288);                 // 8
    float*              lossp = ws + 9740296;                         // 2,048
    // total ≈ 39 MB

    float* zq       = out;                   // [8,256,32,32] NCHW
    float* out_loss = out + 2097152;         // scalar
    float* out_idx  = out + 2097153;         // [8192] as float32

    k_zprep<<<dim3(32, 8, 8), 256, 0, stream>>>(z, zf, zb);
    k_eprep<<<dim3(4096), 256, 0, stream>>>(emb, eb, enorm, gcnt);
    k_rownorm<<<dim3(2048), 256, 0, stream>>>(zf, znorm);
    k_score<<<dim3(1024), 256, 0, stream>>>(zb, eb, enorm, pvalh);
    k_flag<<<dim3(8192), 256, 0, stream>>>(pvalh, best64, wl, gcnt);
    k_rescore<<<dim3(2048), 256, 0, stream>>>(zf, emb, znorm, enorm, wl, gcnt, best64);
    k_finalidx<<<dim3(32), 256, 0, stream>>>(best64, out_idx);
    k_gather<<<dim3(32, 8, 8), 256, 0, stream>>>(emb, zf, best64, zq, lossp);
    k_final<<<1, 256, 0, stream>>>(lossp, out_loss);
}

// Round 9
// 390.940 us; speedup vs baseline: 1.2256x; 1.2256x over previous
//
#include <hip/hip_runtime.h>
#include <hip/hip_fp16.h>

#define DIM 256
#define MARGIN 2.25e-4f
#define WLCAP 262144

typedef __bf16 bf8v __attribute__((ext_vector_type(8)));
typedef float f4v __attribute__((ext_vector_type(4)));

__device__ inline unsigned short f2bf(float x) {
    unsigned u = __float_as_uint(x);
    u += 0x7fffu + ((u >> 16) & 1u);   // RNE
    return (unsigned short)(u >> 16);
}

// ---------------- fused prep ----------------
// seg [0,2048):    transpose z -> zf fp32 + zb bf16
// seg [2048,6144): emb -> eb bf16 + enorm
// seg [6144,6176): znorm directly from z (NCHW reads, coalesced over hw)
// seg [6176,6208): init best64 = ~0, gcnt = 0
__global__ __launch_bounds__(256) void k_prep(const float* __restrict__ z,
                                              const float* __restrict__ emb,
                                              float* __restrict__ zf,
                                              unsigned short* __restrict__ zb,
                                              unsigned short* __restrict__ eb,
                                              float* __restrict__ enorm,
                                              float* __restrict__ znorm,
                                              unsigned long long* __restrict__ best64,
                                              int* __restrict__ gcnt) {
    const int bx = blockIdx.x;
    if (bx < 2048) {
        __shared__ float tt[32][33];
        const int hw0 = (bx & 31) * 32;
        const int d0  = ((bx >> 5) & 7) * 32;
        const int b   = bx >> 8;
        const int tx = threadIdx.x & 31, ty = threadIdx.x >> 5;
#pragma unroll
        for (int i = 0; i < 4; i++) {
            const int d = d0 + ty + 8 * i;
            tt[ty + 8 * i][tx] = z[(b * 256 + d) * 1024 + hw0 + tx];
        }
        __syncthreads();
#pragma unroll
        for (int i = 0; i < 4; i++) {
            const int hw = hw0 + ty + 8 * i;
            const float v = tt[tx][ty + 8 * i];
            const size_t o = (size_t)(b * 1024 + hw) * DIM + d0 + tx;
            zf[o] = v;
            zb[o] = f2bf(v);
        }
    } else if (bx < 6144) {
        const int s = bx - 2048;
        const int wave = threadIdx.x >> 6, lane = threadIdx.x & 63;
        const int row = s * 4 + wave;
        const float4 v = *(const float4*)(emb + (size_t)row * DIM + lane * 4);
        ushort4 o;
        o.x = f2bf(v.x); o.y = f2bf(v.y); o.z = f2bf(v.z); o.w = f2bf(v.w);
        *(ushort4*)(eb + (size_t)row * DIM + lane * 4) = o;
        float ss = v.x * v.x + v.y * v.y + v.z * v.z + v.w * v.w;
#pragma unroll
        for (int m = 1; m < 64; m <<= 1) ss += __shfl_xor(ss, m, 64);
        if (lane == 0) enorm[row] = ss;
    } else if (bx < 6176) {
        const int s = bx - 6144;           // 32 blocks
        const int b = s >> 2, hw0 = (s & 3) * 256;
        const int hw = hw0 + threadIdx.x;
        float acc = 0.f;
        const float* zp = z + (size_t)b * 256 * 1024 + hw;
#pragma unroll 4
        for (int d = 0; d < 256; d++) {
            const float v = zp[d * 1024];
            acc = fmaf(v, v, acc);
        }
        znorm[b * 1024 + hw] = acc;
    } else {
        const int s = bx - 6176;           // 32 blocks
        best64[s * 256 + threadIdx.x] = 0xFFFFFFFFFFFFFFFFULL;
        if (s == 0 && threadIdx.x == 0) gcnt[0] = 0;
    }
}

// ---------------- bf16 MFMA scoring: A full-K in LDS (swizzled), B from L2, 1 barrier ----------
// Block: 128 rows x 128 cols. Wave (wr,wc) covers rows wr*64+.., cols wc*64+..
// Group g = by*8 + wc*4 + (m15>>2): codes by*128 + wc*64 + ct*16 + (m15>>2)*4 + l
// pvalh[row][g] = fp16( min over the group's 16 codes of (en - 2*dot_bf16) )
__global__ __launch_bounds__(256, 2) void k_score(
        const unsigned short* __restrict__ zb, const unsigned short* __restrict__ eb,
        const float* __restrict__ enorm, unsigned short* __restrict__ pvalh) {
    __shared__ unsigned short As[128 * 256];   // 64 KB, swizzled: slot = chunk ^ (r&15)
    __shared__ unsigned short sm[128 * 8];     // 2 KB
    const int row0 = blockIdx.x * 128;
    const int by   = blockIdx.y;
    const int col0 = by * 128;
    const int t = threadIdx.x;
    const int lane = t & 63, wave = t >> 6;
    const int wr = wave >> 1, wc = wave & 1;
    const int q = lane >> 4, m15 = lane & 15;

    // stage A: 128 rows x 512 B = 4096 16B-chunks; source-permuted so LDS holds the swizzle
#pragma unroll
    for (int j = 0; j < 16; j++) {
        const int id = j * 256 + t;
        const int r = id >> 5, sl = id & 31;
        const int c = sl ^ (r & 15);
        __builtin_amdgcn_global_load_lds(
            (const __attribute__((address_space(1))) void*)(zb + (size_t)(row0 + r) * DIM + c * 8),
            (__attribute__((address_space(3))) void*)((char*)As + id * 16), 16, 0, 0);
    }
    __syncthreads();   // the only barrier before epilogue

    f4v acc[4][4];
#pragma unroll
    for (int rt = 0; rt < 4; rt++)
#pragma unroll
        for (int ct = 0; ct < 4; ct++) acc[rt][ct] = (f4v){0.f, 0.f, 0.f, 0.f};

    const unsigned short* brow = eb + (size_t)(col0 + wc * 64 + m15) * DIM + q * 8;

#pragma unroll
    for (int kk = 0; kk < 8; kk++) {
        bf8v af[4], bfv[4];
#pragma unroll
        for (int rt = 0; rt < 4; rt++) {
            const int r = wr * 64 + rt * 16 + m15;
            const int slot = (kk * 4 + q) ^ m15;   // (r&15) == m15
            af[rt] = *(const bf8v*)&As[r * 256 + slot * 8];
        }
#pragma unroll
        for (int ct = 0; ct < 4; ct++)
            bfv[ct] = *(const bf8v*)(brow + (size_t)ct * 16 * DIM + kk * 32);
#pragma unroll
        for (int rt = 0; rt < 4; rt++)
#pragma unroll
            for (int ct = 0; ct < 4; ct++)
                acc[rt][ct] = __builtin_amdgcn_mfma_f32_16x16x32_bf16(af[rt], bfv[ct], acc[rt][ct], 0, 0, 0);
    }

    // epilogue: s = en - 2*dot (filter-only); min over ct, then l = m15&3
    float en_l[4];
#pragma unroll
    for (int ct = 0; ct < 4; ct++) en_l[ct] = enorm[col0 + wc * 64 + ct * 16 + m15];
    const int gsl = wc * 4 + (m15 >> 2);
#pragma unroll
    for (int rt = 0; rt < 4; rt++) {
        float sv[4];
#pragma unroll
        for (int j = 0; j < 4; j++) {
            float s = fmaf(-2.f, acc[rt][0][j], en_l[0]);
#pragma unroll
            for (int ct = 1; ct < 4; ct++)
                s = fminf(s, fmaf(-2.f, acc[rt][ct][j], en_l[ct]));
            sv[j] = s;
        }
#pragma unroll
        for (int m = 1; m <= 2; m <<= 1)
#pragma unroll
            for (int j = 0; j < 4; j++)
                sv[j] = fminf(sv[j], __shfl_xor(sv[j], m, 64));
        if ((m15 & 3) == 0) {
            const int rl = wr * 64 + rt * 16 + q * 4;
#pragma unroll
            for (int j = 0; j < 4; j++)
                sm[(rl + j) * 8 + gsl] = __half_as_ushort(__float2half_rn(sv[j]));
        }
    }
    __syncthreads();
    if (t < 128) {
        const uint4 v = *(const uint4*)&sm[t * 8];
        *(uint4*)&pvalh[(size_t)(row0 + t) * 1024 + by * 8] = v;
    }
}

// ---------------- flag: per row, min over 1024 group-mins; append flagged to worklist ------------
__global__ __launch_bounds__(256) void k_flag(const unsigned short* __restrict__ pvalh,
                                              int* __restrict__ wl, int* __restrict__ gcnt) {
    const int row = blockIdx.x;
    const int t = threadIdx.x;
    const int lane = t & 63, w = t >> 6;
    __shared__ float wmin[4];
    __shared__ int lcnt, lbase;
    __shared__ int llist[1024];
    if (t == 0) lcnt = 0;
    const __half* p = (const __half*)(pvalh + (size_t)row * 1024 + t * 4);
    float v[4];
#pragma unroll
    for (int k = 0; k < 4; k++) v[k] = __half2float(p[k]);
    float mn = fminf(fminf(v[0], v[1]), fminf(v[2], v[3]));
#pragma unroll
    for (int m = 1; m < 64; m <<= 1) mn = fminf(mn, __shfl_xor(mn, m, 64));
    if (lane == 0) wmin[w] = mn;
    __syncthreads();
    const float g = fminf(fminf(wmin[0], wmin[1]), fminf(wmin[2], wmin[3])) + MARGIN;
#pragma unroll
    for (int k = 0; k < 4; k++) {
        if (v[k] <= g) {
            const int pos = atomicAdd(&lcnt, 1);
            llist[pos] = (row << 10) | (t * 4 + k);
        }
    }
    __syncthreads();
    if (t == 0) lbase = atomicAdd(gcnt, lcnt);
    __syncthreads();
    for (int i = t; i < lcnt; i += 256) {
        const int d = lbase + i;
        if (d < WLCAP) wl[d] = llist[i];
    }
}

// ---------------- rescore: exact fp32 re-score of flagged 16-code groups ----------------
__global__ __launch_bounds__(256) void k_rescore(
        const float* __restrict__ zf, const float* __restrict__ emb,
        const float* __restrict__ znorm, const float* __restrict__ enorm,
        const int* __restrict__ wl, const int* __restrict__ gcnt,
        unsigned long long* __restrict__ best64) {
    const int count = min(gcnt[0], WLCAP);
    const int t = threadIdx.x;
    const int lane16 = t & 15, codei = t >> 4;
    for (int item = blockIdx.x; item < count; item += gridDim.x) {
        const int e = wl[item];
        const int row = e >> 10, g = e & 1023;
        // code = (g>>3)*128 + ((g>>2)&1)*64 + ct*16 + (g&3)*4 + l,  codei = ct*4 + l
        const int cbase = ((g >> 3) << 7) + (((g >> 2) & 1) << 6) + ((g & 3) << 2);
        const int code = cbase + ((codei >> 2) << 4) + (codei & 3);
        const float* zp = zf + (size_t)row * DIM + lane16 * 16;
        const float* ep = emb + (size_t)code * DIM + lane16 * 16;
        float d = 0.f;
#pragma unroll
        for (int k = 0; k < 16; k += 4) {
            const float4 ev = *(const float4*)(ep + k);
            const float4 zv = *(const float4*)(zp + k);
            d = fmaf(zv.x, ev.x, d);
            d = fmaf(zv.y, ev.y, d);
            d = fmaf(zv.z, ev.z, d);
            d = fmaf(zv.w, ev.w, d);
        }
#pragma unroll
        for (int m = 1; m <= 8; m <<= 1) d += __shfl_xor(d, m, 64);
        if (lane16 == 0) {
            const float tt = znorm[row] + enorm[code];
            const float s = tt - 2.0f * d;   // exact fp32 semantics
            const unsigned long long key =
                ((unsigned long long)__float_as_uint(s) << 32) | (unsigned)code;
            atomicMin(&best64[row], key);
        }
    }
}

// ---------------- gather z_q (NCHW) + loss partials + out_idx ----------------
__global__ __launch_bounds__(256) void k_gather(const float* __restrict__ emb,
                                                const float* __restrict__ zf,
                                                const unsigned long long* __restrict__ best64,
                                                float* __restrict__ zq,
                                                float* __restrict__ loss_part,
                                                float* __restrict__ out_idx) {
    __shared__ float t[32][33];
    const int hw0 = blockIdx.x * 32;
    const int c0  = blockIdx.y * 32;
    const int b   = blockIdx.z;
    const int tx = threadIdx.x & 31, ty = threadIdx.x >> 5;
    float lsum = 0.f;
#pragma unroll
    for (int i = 0; i < 4; i++) {
        const int hh = ty + 8 * i;
        const int n = b * 1024 + hw0 + hh;
        const int id = (int)(best64[n] & 0xFFFFFFFFULL);
        const float q = emb[(size_t)id * DIM + c0 + tx];
        const float zv = zf[(size_t)n * DIM + c0 + tx];
        const float d = q - zv;
        lsum += d * d;
        t[hh][tx] = q;
    }
    __syncthreads();
#pragma unroll
    for (int i = 0; i < 4; i++) {
        const int c = c0 + ty + 8 * i;
        zq[(size_t)(b * 256 + c) * 1024 + hw0 + tx] = t[tx][ty + 8 * i];
    }
    if (blockIdx.y == 0 && threadIdx.x < 32) {
        const int n = b * 1024 + hw0 + threadIdx.x;
        out_idx[n] = (float)(unsigned)(best64[n] & 0xFFFFFFFFULL);
    }
#pragma unroll
    for (int m = 1; m < 64; m <<= 1) lsum += __shfl_xor(lsum, m, 64);
    __shared__ float wsum[4];
    const int lane = threadIdx.x & 63, w = threadIdx.x >> 6;
    if (lane == 0) wsum[w] = lsum;
    __syncthreads();
    if (threadIdx.x == 0) {
        const int bid = (blockIdx.z * gridDim.y + blockIdx.y) * gridDim.x + blockIdx.x;
        loss_part[bid] = wsum[0] + wsum[1] + wsum[2] + wsum[3];
    }
}

// ---------------- finalize loss ----------------
__global__ __launch_bounds__(256) void k_final(const float* __restrict__ loss_part,
                                               float* __restrict__ out_loss) {
    float s = 0.f;
    for (int i = threadIdx.x; i < 2048; i += 256) s += loss_part[i];
#pragma unroll
    for (int m = 1; m < 64; m <<= 1) s += __shfl_xor(s, m, 64);
    __shared__ float wsum[4];
    const int lane = threadIdx.x & 63, w = threadIdx.x >> 6;
    if (lane == 0) wsum[w] = s;
    __syncthreads();
    if (threadIdx.x == 0) {
        out_loss[0] = 1.25f * (wsum[0] + wsum[1] + wsum[2] + wsum[3]) / 2097152.0f;
    }
}

extern "C" void kernel_launch(void* const* d_in, const int* in_sizes, int n_in,
                              void* d_out, int out_size, void* d_ws, size_t ws_size,
                              hipStream_t stream) {
    const float* z   = (const float*)d_in[0];   // [8,256,32,32]
    const float* emb = (const float*)d_in[1];   // [16384,256]
    float* out = (float*)d_out;
    float* ws  = (float*)d_ws;

    // ws layout (float-slot offsets):
    float*              zf    = ws;                                   // 2,097,152  (8 MB)
    unsigned short*     pvalh = (unsigned short*)(ws + 2097152);      // 8M halves  (16 MB)
    unsigned short*     zb    = (unsigned short*)(ws + 6291456);      // 2M halves  (4 MB)
    unsigned short*     eb    = (unsigned short*)(ws + 7340032);      // 4M halves  (8 MB)
    float*              enorm = ws + 9437184;                         // 16,384
    float*              znorm = ws + 9453568;                         // 8,192
    unsigned long long* best64= (unsigned long long*)(ws + 9461760);  // 8192 × 8 B
    int*                wl    = (int*)(ws + 9478144);                 // 262,144
    int*                gcnt  = (int*)(ws + 9740288);                 // 8
    float*              lossp = ws + 9740296;                         // 2,048
    // total ≈ 39 MB

    float* zq       = out;                   // [8,256,32,32] NCHW
    float* out_loss = out + 2097152;         // scalar
    float* out_idx  = out + 2097153;         // [8192] as float32

    k_prep<<<dim3(6208), 256, 0, stream>>>(z, emb, zf, zb, eb, enorm, znorm, best64, gcnt);
    k_score<<<dim3(64, 128), 256, 0, stream>>>(zb, eb, enorm, pvalh);
    k_flag<<<dim3(8192), 256, 0, stream>>>(pvalh, wl, gcnt);
    k_rescore<<<dim3(2048), 256, 0, stream>>>(zf, emb, znorm, enorm, wl, gcnt, best64);
    k_gather<<<dim3(32, 8, 8), 256, 0, stream>>>(emb, zf, best64, zq, lossp, out_idx);
    k_final<<<1, 256, 0, stream>>>(lossp, out_loss);
}

// Round 10
// 369.730 us; speedup vs baseline: 1.2959x; 1.0574x over previous
//
#include <hip/hip_runtime.h>
#include <hip/hip_fp16.h>

#define DIM 256
#define MARGIN 2.25e-4f
#define WLCAP 262144

typedef __bf16 bf8v __attribute__((ext_vector_type(8)));
typedef float f4v __attribute__((ext_vector_type(4)));

__device__ inline unsigned short f2bf(float x) {
    unsigned u = __float_as_uint(x);
    u += 0x7fffu + ((u >> 16) & 1u);   // RNE
    return (unsigned short)(u >> 16);
}

// ---------------- fused prep ----------------
__global__ __launch_bounds__(256) void k_prep(const float* __restrict__ z,
                                              const float* __restrict__ emb,
                                              float* __restrict__ zf,
                                              unsigned short* __restrict__ zb,
                                              unsigned short* __restrict__ eb,
                                              float* __restrict__ enorm,
                                              float* __restrict__ znorm,
                                              unsigned long long* __restrict__ best64,
                                              int* __restrict__ gcnt) {
    const int bx = blockIdx.x;
    if (bx < 2048) {
        __shared__ float tt[32][33];
        const int hw0 = (bx & 31) * 32;
        const int d0  = ((bx >> 5) & 7) * 32;
        const int b   = bx >> 8;
        const int tx = threadIdx.x & 31, ty = threadIdx.x >> 5;
#pragma unroll
        for (int i = 0; i < 4; i++) {
            const int d = d0 + ty + 8 * i;
            tt[ty + 8 * i][tx] = z[(b * 256 + d) * 1024 + hw0 + tx];
        }
        __syncthreads();
#pragma unroll
        for (int i = 0; i < 4; i++) {
            const int hw = hw0 + ty + 8 * i;
            const float v = tt[tx][ty + 8 * i];
            const size_t o = (size_t)(b * 1024 + hw) * DIM + d0 + tx;
            zf[o] = v;
            zb[o] = f2bf(v);
        }
    } else if (bx < 6144) {
        const int s = bx - 2048;
        const int wave = threadIdx.x >> 6, lane = threadIdx.x & 63;
        const int row = s * 4 + wave;
        const float4 v = *(const float4*)(emb + (size_t)row * DIM + lane * 4);
        ushort4 o;
        o.x = f2bf(v.x); o.y = f2bf(v.y); o.z = f2bf(v.z); o.w = f2bf(v.w);
        *(ushort4*)(eb + (size_t)row * DIM + lane * 4) = o;
        float ss = v.x * v.x + v.y * v.y + v.z * v.z + v.w * v.w;
#pragma unroll
        for (int m = 1; m < 64; m <<= 1) ss += __shfl_xor(ss, m, 64);
        if (lane == 0) enorm[row] = ss;
    } else if (bx < 6176) {
        const int s = bx - 6144;
        const int b = s >> 2, hw0 = (s & 3) * 256;
        const int hw = hw0 + threadIdx.x;
        float acc = 0.f;
        const float* zp = z + (size_t)b * 256 * 1024 + hw;
#pragma unroll 4
        for (int d = 0; d < 256; d++) {
            const float v = zp[d * 1024];
            acc = fmaf(v, v, acc);
        }
        znorm[b * 1024 + hw] = acc;
    } else {
        const int s = bx - 6176;
        best64[s * 256 + threadIdx.x] = 0xFFFFFFFFFFFFFFFFULL;
        if (s == 0 && threadIdx.x == 0) gcnt[0] = 0;
    }
}

// ---------------- bf16 MFMA scoring: 64-row A in LDS (swizzled), B from L2, 4 blocks/CU --------
// Grid col-major: by = blockIdx.x >> 7 (co-resident blocks share B slice -> XCD-L2 locality).
// Block: 64 rows x 256 cols; wave wc covers cols [wc*64, +64).
// Group g = by*16 + wc*4 + (m15>>2): codes by*256 + wc*64 + ct*16 + (m15>>2)*4 + l
__global__ __launch_bounds__(256, 4) void k_score(
        const unsigned short* __restrict__ zb, const unsigned short* __restrict__ eb,
        const float* __restrict__ enorm, unsigned short* __restrict__ pvalh) {
    __shared__ unsigned short As[64 * 256];   // 32 KB, swizzled: slot = chunk ^ (r&15)
    __shared__ unsigned short sm[64 * 16];    // 2 KB
    const int rx = blockIdx.x & 127;
    const int by = blockIdx.x >> 7;
    const int row0 = rx * 64;
    const int col0 = by * 256;
    const int t = threadIdx.x;
    const int lane = t & 63, wc = t >> 6;
    const int q = lane >> 4, m15 = lane & 15;

    // stage A: 64 rows x 512 B = 2048 16B-chunks, source-permuted swizzle
#pragma unroll
    for (int j = 0; j < 8; j++) {
        const int id = j * 256 + t;
        const int r = id >> 5, sl = id & 31;
        const int c = sl ^ (r & 15);
        __builtin_amdgcn_global_load_lds(
            (const __attribute__((address_space(1))) void*)(zb + (size_t)(row0 + r) * DIM + c * 8),
            (__attribute__((address_space(3))) void*)((char*)As + id * 16), 16, 0, 0);
    }
    __syncthreads();   // the only barrier before epilogue

    f4v acc[4][4];
#pragma unroll
    for (int rt = 0; rt < 4; rt++)
#pragma unroll
        for (int ct = 0; ct < 4; ct++) acc[rt][ct] = (f4v){0.f, 0.f, 0.f, 0.f};

    const unsigned short* brow = eb + (size_t)(col0 + wc * 64 + m15) * DIM + q * 8;

#pragma unroll
    for (int kk = 0; kk < 8; kk++) {
        bf8v af[4], bfv[4];
#pragma unroll
        for (int rt = 0; rt < 4; rt++) {
            const int r = rt * 16 + m15;
            const int slot = (kk * 4 + q) ^ m15;   // (r&15) == m15
            af[rt] = *(const bf8v*)&As[r * 256 + slot * 8];
        }
#pragma unroll
        for (int ct = 0; ct < 4; ct++)
            bfv[ct] = *(const bf8v*)(brow + (size_t)ct * 16 * DIM + kk * 32);
#pragma unroll
        for (int rt = 0; rt < 4; rt++)
#pragma unroll
            for (int ct = 0; ct < 4; ct++)
                acc[rt][ct] = __builtin_amdgcn_mfma_f32_16x16x32_bf16(af[rt], bfv[ct], acc[rt][ct], 0, 0, 0);
    }

    // epilogue: s = en - 2*dot (filter-only); min over ct, then l = m15&3
    float en_l[4];
#pragma unroll
    for (int ct = 0; ct < 4; ct++) en_l[ct] = enorm[col0 + wc * 64 + ct * 16 + m15];
    const int gsl = wc * 4 + (m15 >> 2);
#pragma unroll
    for (int rt = 0; rt < 4; rt++) {
        float sv[4];
#pragma unroll
        for (int j = 0; j < 4; j++) {
            float s = fmaf(-2.f, acc[rt][0][j], en_l[0]);
#pragma unroll
            for (int ct = 1; ct < 4; ct++)
                s = fminf(s, fmaf(-2.f, acc[rt][ct][j], en_l[ct]));
            sv[j] = s;
        }
#pragma unroll
        for (int m = 1; m <= 2; m <<= 1)
#pragma unroll
            for (int j = 0; j < 4; j++)
                sv[j] = fminf(sv[j], __shfl_xor(sv[j], m, 64));
        if ((m15 & 3) == 0) {
            const int rl = rt * 16 + q * 4;
#pragma unroll
            for (int j = 0; j < 4; j++)
                sm[(rl + j) * 16 + gsl] = __half_as_ushort(__float2half_rn(sv[j]));
        }
    }
    __syncthreads();
    if (t < 128) {
        const uint4 v = *(const uint4*)&sm[t * 8];
        *(uint4*)&pvalh[(size_t)(row0 + (t >> 1)) * 1024 + by * 16 + (t & 1) * 8] = v;
    }
}

// ---------------- flag: wave-per-row (4 rows/block); append flagged groups to worklist ----------
__global__ __launch_bounds__(256) void k_flag(const unsigned short* __restrict__ pvalh,
                                              int* __restrict__ wl, int* __restrict__ gcnt) {
    const int w = threadIdx.x >> 6, lane = threadIdx.x & 63;
    const int row = blockIdx.x * 4 + w;
    __shared__ int lcnt[4], lbase[4];
    __shared__ int llist[4][1024];
    if (lane == 0) lcnt[w] = 0;
    __syncthreads();
    const unsigned short* p = pvalh + (size_t)row * 1024;
    const uint4 u0 = *(const uint4*)(p + lane * 8);
    const uint4 u1 = *(const uint4*)(p + 512 + lane * 8);
    const __half* h0 = (const __half*)&u0;
    const __half* h1 = (const __half*)&u1;
    float v[16];
    float mn = 3.0e38f;
#pragma unroll
    for (int k = 0; k < 8; k++) {
        v[k] = __half2float(h0[k]);
        v[8 + k] = __half2float(h1[k]);
        mn = fminf(mn, fminf(v[k], v[8 + k]));
    }
#pragma unroll
    for (int m = 1; m < 64; m <<= 1) mn = fminf(mn, __shfl_xor(mn, m, 64));
    const float g = mn + MARGIN;
#pragma unroll
    for (int k = 0; k < 8; k++) {
        if (v[k] <= g) {
            const int pos = atomicAdd(&lcnt[w], 1);
            llist[w][pos] = (row << 10) | (lane * 8 + k);
        }
        if (v[8 + k] <= g) {
            const int pos = atomicAdd(&lcnt[w], 1);
            llist[w][pos] = (row << 10) | (512 + lane * 8 + k);
        }
    }
    __syncthreads();
    if (lane == 0) lbase[w] = atomicAdd(gcnt, lcnt[w]);
    __syncthreads();
    const int n = lcnt[w], base = lbase[w];
    for (int i = lane; i < n; i += 64) {
        const int d = base + i;
        if (d < WLCAP) wl[d] = llist[w][i];
    }
}

// ---------------- rescore: exact fp32 re-score of flagged 16-code groups ----------------
__global__ __launch_bounds__(256) void k_rescore(
        const float* __restrict__ zf, const float* __restrict__ emb,
        const float* __restrict__ znorm, const float* __restrict__ enorm,
        const int* __restrict__ wl, const int* __restrict__ gcnt,
        unsigned long long* __restrict__ best64) {
    const int count = min(gcnt[0], WLCAP);
    const int t = threadIdx.x;
    const int lane16 = t & 15, codei = t >> 4;
    for (int item = blockIdx.x; item < count; item += gridDim.x) {
        const int e = wl[item];
        const int row = e >> 10, g = e & 1023;
        // code = (g>>4)*256 + ((g>>2)&3)*64 + ct*16 + (g&3)*4 + l,  codei = ct*4 + l
        const int cbase = ((g >> 4) << 8) + (((g >> 2) & 3) << 6) + ((g & 3) << 2);
        const int code = cbase + ((codei >> 2) << 4) + (codei & 3);
        const float* zp = zf + (size_t)row * DIM + lane16 * 16;
        const float* ep = emb + (size_t)code * DIM + lane16 * 16;
        float d = 0.f;
#pragma unroll
        for (int k = 0; k < 16; k += 4) {
            const float4 ev = *(const float4*)(ep + k);
            const float4 zv = *(const float4*)(zp + k);
            d = fmaf(zv.x, ev.x, d);
            d = fmaf(zv.y, ev.y, d);
            d = fmaf(zv.z, ev.z, d);
            d = fmaf(zv.w, ev.w, d);
        }
#pragma unroll
        for (int m = 1; m <= 8; m <<= 1) d += __shfl_xor(d, m, 64);
        if (lane16 == 0) {
            const float tt = znorm[row] + enorm[code];
            const float s = tt - 2.0f * d;   // exact fp32 semantics
            const unsigned long long key =
                ((unsigned long long)__float_as_uint(s) << 32) | (unsigned)code;
            atomicMin(&best64[row], key);
        }
    }
}

// ---------------- gather z_q (NCHW) + loss partials + out_idx ----------------
__global__ __launch_bounds__(256) void k_gather(const float* __restrict__ emb,
                                                const float* __restrict__ zf,
                                                const unsigned long long* __restrict__ best64,
                                                float* __restrict__ zq,
                                                float* __restrict__ loss_part,
                                                float* __restrict__ out_idx) {
    __shared__ float t[32][33];
    const int hw0 = blockIdx.x * 32;
    const int c0  = blockIdx.y * 32;
    const int b   = blockIdx.z;
    const int tx = threadIdx.x & 31, ty = threadIdx.x >> 5;
    float lsum = 0.f;
#pragma unroll
    for (int i = 0; i < 4; i++) {
        const int hh = ty + 8 * i;
        const int n = b * 1024 + hw0 + hh;
        const int id = (int)(best64[n] & 0xFFFFFFFFULL);
        const float q = emb[(size_t)id * DIM + c0 + tx];
        const float zv = zf[(size_t)n * DIM + c0 + tx];
        const float d = q - zv;
        lsum += d * d;
        t[hh][tx] = q;
    }
    __syncthreads();
#pragma unroll
    for (int i = 0; i < 4; i++) {
        const int c = c0 + ty + 8 * i;
        zq[(size_t)(b * 256 + c) * 1024 + hw0 + tx] = t[tx][ty + 8 * i];
    }
    if (blockIdx.y == 0 && threadIdx.x < 32) {
        const int n = b * 1024 + hw0 + threadIdx.x;
        out_idx[n] = (float)(unsigned)(best64[n] & 0xFFFFFFFFULL);
    }
#pragma unroll
    for (int m = 1; m < 64; m <<= 1) lsum += __shfl_xor(lsum, m, 64);
    __shared__ float wsum[4];
    const int lane = threadIdx.x & 63, w = threadIdx.x >> 6;
    if (lane == 0) wsum[w] = lsum;
    __syncthreads();
    if (threadIdx.x == 0) {
        const int bid = (blockIdx.z * gridDim.y + blockIdx.y) * gridDim.x + blockIdx.x;
        loss_part[bid] = wsum[0] + wsum[1] + wsum[2] + wsum[3];
    }
}

// ---------------- finalize loss ----------------
__global__ __launch_bounds__(256) void k_final(const float* __restrict__ loss_part,
                                               float* __restrict__ out_loss) {
    float s = 0.f;
    for (int i = threadIdx.x; i < 2048; i += 256) s += loss_part[i];
#pragma unroll
    for (int m = 1; m < 64; m <<= 1) s += __shfl_xor(s, m, 64);
    __shared__ float wsum[4];
    const int lane = threadIdx.x & 63, w = threadIdx.x >> 6;
    if (lane == 0) wsum[w] = s;
    __syncthreads();
    if (threadIdx.x == 0) {
        out_loss[0] = 1.25f * (wsum[0] + wsum[1] + wsum[2] + wsum[3]) / 2097152.0f;
    }
}

extern "C" void kernel_launch(void* const* d_in, const int* in_sizes, int n_in,
                              void* d_out, int out_size, void* d_ws, size_t ws_size,
                              hipStream_t stream) {
    const float* z   = (const float*)d_in[0];   // [8,256,32,32]
    const float* emb = (const float*)d_in[1];   // [16384,256]
    float* out = (float*)d_out;
    float* ws  = (float*)d_ws;

    // ws layout (float-slot offsets):
    float*              zf    = ws;                                   // 2,097,152  (8 MB)
    unsigned short*     pvalh = (unsigned short*)(ws + 2097152);      // 8M halves  (16 MB)
    unsigned short*     zb    = (unsigned short*)(ws + 6291456);      // 2M halves  (4 MB)
    unsigned short*     eb    = (unsigned short*)(ws + 7340032);      // 4M halves  (8 MB)
    float*              enorm = ws + 9437184;                         // 16,384
    float*              znorm = ws + 9453568;                         // 8,192
    unsigned long long* best64= (unsigned long long*)(ws + 9461760);  // 8192 × 8 B
    int*                wl    = (int*)(ws + 9478144);                 // 262,144
    int*                gcnt  = (int*)(ws + 9740288);                 // 8
    float*              lossp = ws + 9740296;                         // 2,048
    // total ≈ 39 MB

    float* zq       = out;                   // [8,256,32,32] NCHW
    float* out_loss = out + 2097152;         // scalar
    float* out_idx  = out + 2097153;         // [8192] as float32

    k_prep<<<dim3(6208), 256, 0, stream>>>(z, emb, zf, zb, eb, enorm, znorm, best64, gcnt);
    k_score<<<dim3(8192), 256, 0, stream>>>(zb, eb, enorm, pvalh);
    k_flag<<<dim3(2048), 256, 0, stream>>>(pvalh, wl, gcnt);
    k_rescore<<<dim3(2048), 256, 0, stream>>>(zf, emb, znorm, enorm, wl, gcnt, best64);
    k_gather<<<dim3(32, 8, 8), 256, 0, stream>>>(emb, zf, best64, zq, lossp, out_idx);
    k_final<<<1, 256, 0, stream>>>(lossp, out_loss);
}

// Round 11
// 276.157 us; speedup vs baseline: 1.7350x; 1.3388x over previous
//
#include <hip/hip_runtime.h>
#include <hip/hip_fp16.h>

#define DIM 256
#define MARGIN 2.25e-4f

typedef __bf16 bf8v __attribute__((ext_vector_type(8)));
typedef float f4v __attribute__((ext_vector_type(4)));

__device__ inline unsigned short f2bf(float x) {
    unsigned u = __float_as_uint(x);
    u += 0x7fffu + ((u >> 16) & 1u);   // RNE
    return (unsigned short)(u >> 16);
}

// ---------------- fused prep ----------------
// [0,2048):    transpose z -> zf fp32 + zb bf16
// [2048,6144): emb -> eb bf16 + enorm
// 6144:        zero out_loss (d_out is poisoned 0xAA before every launch)
__global__ __launch_bounds__(256) void k_prep(const float* __restrict__ z,
                                              const float* __restrict__ emb,
                                              float* __restrict__ zf,
                                              unsigned short* __restrict__ zb,
                                              unsigned short* __restrict__ eb,
                                              float* __restrict__ enorm,
                                              float* __restrict__ out_loss) {
    const int bx = blockIdx.x;
    if (bx < 2048) {
        __shared__ float tt[32][33];
        const int hw0 = (bx & 31) * 32;
        const int d0  = ((bx >> 5) & 7) * 32;
        const int b   = bx >> 8;
        const int tx = threadIdx.x & 31, ty = threadIdx.x >> 5;
#pragma unroll
        for (int i = 0; i < 4; i++) {
            const int d = d0 + ty + 8 * i;
            tt[ty + 8 * i][tx] = z[(b * 256 + d) * 1024 + hw0 + tx];
        }
        __syncthreads();
#pragma unroll
        for (int i = 0; i < 4; i++) {
            const int hw = hw0 + ty + 8 * i;
            const float v = tt[tx][ty + 8 * i];
            const size_t o = (size_t)(b * 1024 + hw) * DIM + d0 + tx;
            zf[o] = v;
            zb[o] = f2bf(v);
        }
    } else if (bx < 6144) {
        const int s = bx - 2048;
        const int wave = threadIdx.x >> 6, lane = threadIdx.x & 63;
        const int row = s * 4 + wave;
        const float4 v = *(const float4*)(emb + (size_t)row * DIM + lane * 4);
        ushort4 o;
        o.x = f2bf(v.x); o.y = f2bf(v.y); o.z = f2bf(v.z); o.w = f2bf(v.w);
        *(ushort4*)(eb + (size_t)row * DIM + lane * 4) = o;
        float ss = v.x * v.x + v.y * v.y + v.z * v.z + v.w * v.w;
#pragma unroll
        for (int m = 1; m < 64; m <<= 1) ss += __shfl_xor(ss, m, 64);
        if (lane == 0) enorm[row] = ss;
    } else {
        if (threadIdx.x == 0) out_loss[0] = 0.f;
    }
}

// ---------------- bf16 MFMA scoring: 64-row A in LDS (swizzled), B from L2, 4 blocks/CU --------
// (unchanged from R10 — 142 us, conflict-free A reads, col-major grid for L2 B reuse)
// Group g = by*16 + wc*4 + (m15>>2): codes by*256 + wc*64 + ct*16 + (m15>>2)*4 + l
__global__ __launch_bounds__(256, 4) void k_score(
        const unsigned short* __restrict__ zb, const unsigned short* __restrict__ eb,
        const float* __restrict__ enorm, unsigned short* __restrict__ pvalh) {
    __shared__ unsigned short As[64 * 256];   // 32 KB, swizzled: slot = chunk ^ (r&15)
    __shared__ unsigned short sm[64 * 16];    // 2 KB
    const int rx = blockIdx.x & 127;
    const int by = blockIdx.x >> 7;
    const int row0 = rx * 64;
    const int col0 = by * 256;
    const int t = threadIdx.x;
    const int lane = t & 63, wc = t >> 6;
    const int q = lane >> 4, m15 = lane & 15;

#pragma unroll
    for (int j = 0; j < 8; j++) {
        const int id = j * 256 + t;
        const int r = id >> 5, sl = id & 31;
        const int c = sl ^ (r & 15);
        __builtin_amdgcn_global_load_lds(
            (const __attribute__((address_space(1))) void*)(zb + (size_t)(row0 + r) * DIM + c * 8),
            (__attribute__((address_space(3))) void*)((char*)As + id * 16), 16, 0, 0);
    }
    __syncthreads();

    f4v acc[4][4];
#pragma unroll
    for (int rt = 0; rt < 4; rt++)
#pragma unroll
        for (int ct = 0; ct < 4; ct++) acc[rt][ct] = (f4v){0.f, 0.f, 0.f, 0.f};

    const unsigned short* brow = eb + (size_t)(col0 + wc * 64 + m15) * DIM + q * 8;

#pragma unroll
    for (int kk = 0; kk < 8; kk++) {
        bf8v af[4], bfv[4];
#pragma unroll
        for (int rt = 0; rt < 4; rt++) {
            const int r = rt * 16 + m15;
            const int slot = (kk * 4 + q) ^ m15;
            af[rt] = *(const bf8v*)&As[r * 256 + slot * 8];
        }
#pragma unroll
        for (int ct = 0; ct < 4; ct++)
            bfv[ct] = *(const bf8v*)(brow + (size_t)ct * 16 * DIM + kk * 32);
#pragma unroll
        for (int rt = 0; rt < 4; rt++)
#pragma unroll
            for (int ct = 0; ct < 4; ct++)
                acc[rt][ct] = __builtin_amdgcn_mfma_f32_16x16x32_bf16(af[rt], bfv[ct], acc[rt][ct], 0, 0, 0);
    }

    float en_l[4];
#pragma unroll
    for (int ct = 0; ct < 4; ct++) en_l[ct] = enorm[col0 + wc * 64 + ct * 16 + m15];
    const int gsl = wc * 4 + (m15 >> 2);
#pragma unroll
    for (int rt = 0; rt < 4; rt++) {
        float sv[4];
#pragma unroll
        for (int j = 0; j < 4; j++) {
            float s = fmaf(-2.f, acc[rt][0][j], en_l[0]);
#pragma unroll
            for (int ct = 1; ct < 4; ct++)
                s = fminf(s, fmaf(-2.f, acc[rt][ct][j], en_l[ct]));
            sv[j] = s;
        }
#pragma unroll
        for (int m = 1; m <= 2; m <<= 1)
#pragma unroll
            for (int j = 0; j < 4; j++)
                sv[j] = fminf(sv[j], __shfl_xor(sv[j], m, 64));
        if ((m15 & 3) == 0) {
            const int rl = rt * 16 + q * 4;
#pragma unroll
            for (int j = 0; j < 4; j++)
                sm[(rl + j) * 16 + gsl] = __half_as_ushort(__float2half_rn(sv[j]));
        }
    }
    __syncthreads();
    if (t < 128) {
        const uint4 v = *(const uint4*)&sm[t * 8];
        *(uint4*)&pvalh[(size_t)(row0 + (t >> 1)) * 1024 + by * 16 + (t & 1) * 8] = v;
    }
}

// ---------------- select: per-row flag + exact fp32 rescore + argmin (fused, no worklist) -------
__global__ __launch_bounds__(256) void k_select(
        const float* __restrict__ zf, const float* __restrict__ emb,
        const float* __restrict__ enorm, const unsigned short* __restrict__ pvalh,
        int* __restrict__ idxi, float* __restrict__ out_idx) {
    const int row = blockIdx.x;
    const int t = threadIdx.x;
    const int lane = t & 63, w = t >> 6;
    __shared__ float zs[256];
    __shared__ float wred[4];
    __shared__ int lcnt;
    __shared__ int list[1024];
    __shared__ float fs[16];
    __shared__ int fi[16];

    // load z-row into LDS + row norm (row-constant: order-insensitive for argmin)
    const float zv = zf[(size_t)row * DIM + t];
    zs[t] = zv;
    if (t == 0) lcnt = 0;
    float nrm = zv * zv;
#pragma unroll
    for (int m = 1; m < 64; m <<= 1) nrm += __shfl_xor(nrm, m, 64);
    if (lane == 0) wred[w] = nrm;

    // row group-mins -> global min
    const __half* p = (const __half*)(pvalh + (size_t)row * 1024 + t * 4);
    float v[4];
#pragma unroll
    for (int k = 0; k < 4; k++) v[k] = __half2float(p[k]);
    float mn = fminf(fminf(v[0], v[1]), fminf(v[2], v[3]));
#pragma unroll
    for (int m = 1; m < 64; m <<= 1) mn = fminf(mn, __shfl_xor(mn, m, 64));
    __shared__ float wmin[4];
    if (lane == 0) wmin[w] = mn;
    __syncthreads();
    const float zn = wred[0] + wred[1] + wred[2] + wred[3];
    const float g = fminf(fminf(wmin[0], wmin[1]), fminf(wmin[2], wmin[3])) + MARGIN;
#pragma unroll
    for (int k = 0; k < 4; k++) {
        if (v[k] <= g) {
            const int pos = atomicAdd(&lcnt, 1);
            list[pos] = t * 4 + k;
        }
    }
    __syncthreads();

    // exact fp32 rescore of flagged groups: 16 codes/group, 16 lanes/code
    const int lane16 = t & 15, codei = t >> 4;
    const int n = lcnt;
    float bv = 3.0e38f;
    int bi = 0x7fffffff;
    for (int i = 0; i < n; i++) {
        const int gg = list[i];
        // code = (g>>4)*256 + ((g>>2)&3)*64 + ct*16 + (g&3)*4 + l,  codei = ct*4 + l
        const int cbase = ((gg >> 4) << 8) + (((gg >> 2) & 3) << 6) + ((gg & 3) << 2);
        const int code = cbase + ((codei >> 2) << 4) + (codei & 3);
        const float* zp = zs + lane16 * 16;
        const float* ep = emb + (size_t)code * DIM + lane16 * 16;
        float d = 0.f;
#pragma unroll
        for (int k = 0; k < 16; k += 4) {
            const float4 ev = *(const float4*)(ep + k);
            const float4 zv4 = *(const float4*)(zp + k);
            d = fmaf(zv4.x, ev.x, d);
            d = fmaf(zv4.y, ev.y, d);
            d = fmaf(zv4.z, ev.z, d);
            d = fmaf(zv4.w, ev.w, d);
        }
#pragma unroll
        for (int m = 1; m <= 8; m <<= 1) d += __shfl_xor(d, m, 64);
        if (lane16 == 0) {
            const float tt = zn + enorm[code];
            const float s = tt - 2.0f * d;   // exact fp32 semantics
            if (s < bv || (s == bv && code < bi)) { bv = s; bi = code; }
        }
    }
    if (lane16 == 0) { fs[codei] = bv; fi[codei] = bi; }
    __syncthreads();
    if (t == 0) {
        float b = fs[0]; int c = fi[0];
#pragma unroll
        for (int k = 1; k < 16; k++)
            if (fs[k] < b || (fs[k] == b && fi[k] < c)) { b = fs[k]; c = fi[k]; }
        idxi[row] = c;
        out_idx[row] = (float)c;
    }
}

// ---------------- gather z_q (NCHW) + fused loss (atomicAdd) ----------------
__global__ __launch_bounds__(256) void k_gather(const float* __restrict__ emb,
                                                const float* __restrict__ zf,
                                                const int* __restrict__ idxi,
                                                float* __restrict__ zq,
                                                float* __restrict__ out_loss) {
    __shared__ float t[32][33];
    const int hw0 = blockIdx.x * 32;
    const int c0  = blockIdx.y * 32;
    const int b   = blockIdx.z;
    const int tx = threadIdx.x & 31, ty = threadIdx.x >> 5;
    float lsum = 0.f;
#pragma unroll
    for (int i = 0; i < 4; i++) {
        const int hh = ty + 8 * i;
        const int n = b * 1024 + hw0 + hh;
        const int id = idxi[n];
        const float q = emb[(size_t)id * DIM + c0 + tx];
        const float zv = zf[(size_t)n * DIM + c0 + tx];
        const float d = q - zv;
        lsum += d * d;
        t[hh][tx] = q;
    }
    __syncthreads();
#pragma unroll
    for (int i = 0; i < 4; i++) {
        const int c = c0 + ty + 8 * i;
        zq[(size_t)(b * 256 + c) * 1024 + hw0 + tx] = t[tx][ty + 8 * i];
    }
#pragma unroll
    for (int m = 1; m < 64; m <<= 1) lsum += __shfl_xor(lsum, m, 64);
    __shared__ float wsum[4];
    const int lane = threadIdx.x & 63, w = threadIdx.x >> 6;
    if (lane == 0) wsum[w] = lsum;
    __syncthreads();
    if (threadIdx.x == 0) {
        const float total = wsum[0] + wsum[1] + wsum[2] + wsum[3];
        atomicAdd(out_loss, total * (1.25f / 2097152.0f));
    }
}

extern "C" void kernel_launch(void* const* d_in, const int* in_sizes, int n_in,
                              void* d_out, int out_size, void* d_ws, size_t ws_size,
                              hipStream_t stream) {
    const float* z   = (const float*)d_in[0];   // [8,256,32,32]
    const float* emb = (const float*)d_in[1];   // [16384,256]
    float* out = (float*)d_out;
    float* ws  = (float*)d_ws;

    // ws layout (float-slot offsets):
    float*          zf    = ws;                                   // 2,097,152  (8 MB)
    unsigned short* pvalh = (unsigned short*)(ws + 2097152);      // 8M halves  (16 MB)
    unsigned short* zb    = (unsigned short*)(ws + 6291456);      // 2M halves  (4 MB)
    unsigned short* eb    = (unsigned short*)(ws + 7340032);      // 4M halves  (8 MB)
    float*          enorm = ws + 9437184;                         // 16,384
    int*            idxi  = (int*)(ws + 9453568);                 // 8,192
    // total ≈ 37.9 MB

    float* zq       = out;                   // [8,256,32,32] NCHW
    float* out_loss = out + 2097152;         // scalar
    float* out_idx  = out + 2097153;         // [8192] as float32

    k_prep<<<dim3(6145), 256, 0, stream>>>(z, emb, zf, zb, eb, enorm, out_loss);
    k_score<<<dim3(8192), 256, 0, stream>>>(zb, eb, enorm, pvalh);
    k_select<<<dim3(8192), 256, 0, stream>>>(zf, emb, enorm, pvalh, idxi, out_idx);
    k_gather<<<dim3(32, 8, 8), 256, 0, stream>>>(emb, zf, idxi, zq, out_loss);
}